// Round 13
// baseline (1484.285 us; speedup 1.0000x reference)
//
#include <hip/hip_runtime.h>
#include <stdint.h>
#include <stddef.h>

#define DIM    1024
#define NBATCH 8
#define SEQL   2048
#define JSUM   512
#define SPMAX  2304
#define SPS    768

typedef unsigned long long ull;
typedef __attribute__((ext_vector_type(8))) __bf16 bf16x8;
typedef __attribute__((ext_vector_type(8))) short  short8;
typedef __attribute__((ext_vector_type(4))) float  floatx4;

__device__ __forceinline__ short f2bf(float f) {
  unsigned u = __builtin_bit_cast(unsigned, f);
  u = (u + 0x7fffu + ((u >> 16) & 1u)) >> 16;   // RNE
  return (short)u;
}
__device__ __forceinline__ float bf2f(short s) {
  unsigned u = ((unsigned)(unsigned short)s) << 16;
  return __builtin_bit_cast(float, u);
}

// NOTE: the intrinsic's imm-offset arg applies to BOTH global and LDS
// addresses — always pass 0 and do pointer arithmetic on both sides.
__device__ __forceinline__ void glds16(const short* g, short8* l) {
  __builtin_amdgcn_global_load_lds(
      (const __attribute__((address_space(1))) unsigned int*)g,
      (__attribute__((address_space(3))) unsigned int*)l, 16, 0, 0);
}

// Counted vmcnt wait (T4): never drain to 0 inside the K-loop.
#define VMCNT(n) do { asm volatile("s_waitcnt vmcnt(" #n ")" ::: "memory"); \
                      __builtin_amdgcn_sched_barrier(0); } while (0)

// Raw barrier WITHOUT the implicit s_waitcnt vmcnt(0) of __syncthreads().
__device__ __forceinline__ void barrier_raw() {
  asm volatile("" ::: "memory");
  __builtin_amdgcn_s_barrier();
  asm volatile("" ::: "memory");
}

// ---------------------------------------------------------------------------
// Two-problem GEMM parameter block; mode/swiz are RUNTIME (epilogue-only
// cost) so problems of different modes can share one dispatch (tail fill).
// Blocks with pid < q0.nblk run q0, the rest q1.
// ---------------------------------------------------------------------------
struct GemmP {
  const short* A; ull sA; int ldA;
  const short* B; ull sB; int ldB;
  short* C; ull sC;
  int N, Kd;
  const float* bias;
  float* dst0; int t_lo, t_hi, outT;
  float* dstSp; int t_sp, Spad;
  int gx;      // decode: swiz1 -> tn=(lid>>3)%gx, tm=/gx ; swiz2 -> tm=lid%gx
  int nblk;    // blocks of this problem
  int mode;    // 0: C bf16  1: +bias[n]  2: +bias[m]  3: f32 scatter+bias[n]
  int swiz;    // 1: batch=lid&7 -> XCD pin   2: tm-major, bz=0
};

// ---------------------------------------------------------------------------
// NT GEMM: C[m,n] = sum_k A[m,k]*B[n,k]. Row strides ldA/ldB decoupled from
// Kd (K-trim on zero-padded K).  256x256 tile, BK=64, 512 threads (8 waves,
// 2M x 4N, per-wave 128x64, acc[8][4] = 128 VGPR). LDS 128 KiB: 2 K-tile
// buffers, fragment-major slot (k8,row)=k8*256+row — conflict-free
// (measured 0, R0-R11), glds-linear-compatible.
//
// R12 sync-thinning: R11 counters showed 61.6 us/round vs 13.8 us MFMA floor
// (22%); ~6700 cyc/K-tile dead. R9's 8 barriers/K-tile force all 8 waves to
// burst LDS reads in lockstep then stall into MFMA together. Only 2 barriers
// are load-bearing; per K-tile now 2 phases:
//   phase A (ks=0): read bv0,af(mh0); stage A0'(2 glds); 16 MFMA;
//                   read af(mh1); stage B0'(2 glds); 16 MFMA;
//                   VMCNT(4) [A1,B1 of t landed]; barrier
//   phase B (ks=1): same with A1',B1' stages;
//                   VMCNT(4) [A0',B0' landed]; barrier
// Hazard audit: stages write buf^1 while reads hit buf (no intra-tile LDS
// hazard). Every ds_read is consumed by an MFMA before the phase barrier
// (compiler lgkmcnt), so passing the tile-end barrier implies reads done ->
// next tile's stages (into this buf) are write-after-read safe. Guards are
// per-wave vmcnt; the following barrier extends to all waves. vmcnt never
// drains to 0 except the final tile. Barrier counts are uniform across all
// waves (nt is block-uniform) -> no divergent-barrier hang.
// ---------------------------------------------------------------------------
__global__ __launch_bounds__(512, 2)
void gemm_nt(GemmP q0, GemmP q1)
{
  const int  pid = blockIdx.x;
  const bool s1  = pid >= q0.nblk;
  const GemmP& q = s1 ? q1 : q0;
  const int  lid = s1 ? (pid - q0.nblk) : pid;

  int tn, tm, bz;
  if (q.swiz == 1) {
    bz = lid & 7;
    const int s = lid >> 3;
    tn = s % q.gx;
    tm = s / q.gx;
  } else {            // swiz == 2
    tm = lid % q.gx;
    tn = lid / q.gx;
    bz = 0;
  }

  const short* A  = q.A + (ull)bz * q.sA;
  const short* Bm = q.B + (ull)bz * q.sB;

  const int tid  = threadIdx.x;          // 0..511
  const int wave = tid >> 6, lane = tid & 63;

  __shared__ short8 ldsA[2][2048];   // 2 x 32 KB: slot = k8*256 + row, k8 0..7
  __shared__ short8 ldsB[2][2048];   // 2 x 32 KB

  const int r0  = tid & 255;
  const int k80 = tid >> 8;                         // 0..1
  const short* pA = A  + (long long)(tm * 256 + r0) * q.ldA + k80 * 8;
  const short* pB = Bm + (long long)(tn * 256 + r0) * q.ldB + k80 * 8;

  floatx4 acc[8][4];
#pragma unroll
  for (int i = 0; i < 8; i++)
#pragma unroll
    for (int j = 0; j < 4; j++) acc[i][j] = (floatx4)(0.0f);

  const int wm = (wave >> 2) * 128;   // 2 M-halves of waves
  const int wn = (wave & 3) * 64;     // 4 N-quarters of waves
  const int fr = lane & 15;           // fragment row/col select
  const int fq = lane >> 4;           // k8 select (0..3) within a 32-K step

  const int nt = q.Kd >> 6;           // BK = 64

  // Prologue: stage tile 0's 4 units in consume order A0,B0,A1,B1.
  glds16(pA,      &ldsA[0][tid]);
  glds16(pA + 16, &ldsA[0][tid + 512]);
  glds16(pB,      &ldsB[0][tid]);
  glds16(pB + 16, &ldsB[0][tid + 512]);
  glds16(pA + 32, &ldsA[0][1024 + tid]);
  glds16(pA + 48, &ldsA[0][1024 + tid + 512]);
  glds16(pB + 32, &ldsB[0][1024 + tid]);
  glds16(pB + 48, &ldsB[0][1024 + tid + 512]);
  VMCNT(4);            // A0,B0 landed (A1,B1 still in flight)
  barrier_raw();

  for (int t = 0; t < nt; t++) {
    const short8* LA = ldsA[t & 1];
    const short8* LB = ldsB[t & 1];
    const int  nb   = (t + 1) & 1;
    const int  koff = (t + 1) * 64;
    const bool stg  = (t + 1) < nt;

    bf16x8 af[4], bv[4];

    // ---- phase A: ks=0, both m-halves  (+stage A0',B0' of t+1) ----
    {
      const int ka = fq * 256;
#pragma unroll
      for (int n2 = 0; n2 < 4; n2++)
        bv[n2] = __builtin_bit_cast(bf16x8, LB[ka + wn + n2 * 16 + fr]);
#pragma unroll
      for (int mt = 0; mt < 4; mt++)
        af[mt] = __builtin_bit_cast(bf16x8, LA[ka + wm + mt * 16 + fr]);
      if (stg) {
        glds16(pA + koff,      &ldsA[nb][tid]);
        glds16(pA + koff + 16, &ldsA[nb][tid + 512]);
      }
      __builtin_amdgcn_s_setprio(1);
#pragma unroll
      for (int mt = 0; mt < 4; mt++)
#pragma unroll
        for (int n2 = 0; n2 < 4; n2++)
          acc[mt][n2] = __builtin_amdgcn_mfma_f32_16x16x32_bf16(
              af[mt], bv[n2], acc[mt][n2], 0, 0, 0);
      __builtin_amdgcn_s_setprio(0);
#pragma unroll
      for (int mt = 0; mt < 4; mt++)
        af[mt] = __builtin_bit_cast(bf16x8, LA[ka + wm + 64 + mt * 16 + fr]);
      if (stg) {
        glds16(pB + koff,      &ldsB[nb][tid]);
        glds16(pB + koff + 16, &ldsB[nb][tid + 512]);
      }
      __builtin_amdgcn_s_setprio(1);
#pragma unroll
      for (int mt = 0; mt < 4; mt++)
#pragma unroll
        for (int n2 = 0; n2 < 4; n2++)
          acc[4 + mt][n2] = __builtin_amdgcn_mfma_f32_16x16x32_bf16(
              af[mt], bv[n2], acc[4 + mt][n2], 0, 0, 0);
      __builtin_amdgcn_s_setprio(0);
      if (stg) VMCNT(4); else VMCNT(0);   // A1,B1 of tile t landed
      barrier_raw();
    }

    // ---- phase B: ks=1, both m-halves  (+stage A1',B1') ----
    {
      const int ka = (fq + 4) * 256;
#pragma unroll
      for (int n2 = 0; n2 < 4; n2++)
        bv[n2] = __builtin_bit_cast(bf16x8, LB[ka + wn + n2 * 16 + fr]);
#pragma unroll
      for (int mt = 0; mt < 4; mt++)
        af[mt] = __builtin_bit_cast(bf16x8, LA[ka + wm + mt * 16 + fr]);
      if (stg) {
        glds16(pA + koff + 32, &ldsA[nb][1024 + tid]);
        glds16(pA + koff + 48, &ldsA[nb][1024 + tid + 512]);
      }
      __builtin_amdgcn_s_setprio(1);
#pragma unroll
      for (int mt = 0; mt < 4; mt++)
#pragma unroll
        for (int n2 = 0; n2 < 4; n2++)
          acc[mt][n2] = __builtin_amdgcn_mfma_f32_16x16x32_bf16(
              af[mt], bv[n2], acc[mt][n2], 0, 0, 0);
      __builtin_amdgcn_s_setprio(0);
#pragma unroll
      for (int mt = 0; mt < 4; mt++)
        af[mt] = __builtin_bit_cast(bf16x8, LA[ka + wm + 64 + mt * 16 + fr]);
      if (stg) {
        glds16(pB + koff + 32, &ldsB[nb][1024 + tid]);
        glds16(pB + koff + 48, &ldsB[nb][1024 + tid + 512]);
      }
      __builtin_amdgcn_s_setprio(1);
#pragma unroll
      for (int mt = 0; mt < 4; mt++)
#pragma unroll
        for (int n2 = 0; n2 < 4; n2++)
          acc[4 + mt][n2] = __builtin_amdgcn_mfma_f32_16x16x32_bf16(
              af[mt], bv[n2], acc[4 + mt][n2], 0, 0, 0);
      __builtin_amdgcn_s_setprio(0);
      if (stg) VMCNT(4);                  // A0',B0' landed for next phase A
      barrier_raw();
    }
  }

  // Epilogue.  C/D layout: col = lane&15, row = (lane>>4)*4 + reg  [m89]
  // acc[mf][n2]: row-in-wave = (mf>>2)*64 + (mf&3)*16, col-in-wave = n2*16.
  if (q.mode == 3) {
    // Tiles never straddle batches (Spad % 256 == 0): derive batch once.
    const int bb  = (tm * 256) / q.Spad;
    const int rb0 = tm * 256 - bb * q.Spad + wm + fq * 4;
#pragma unroll
    for (int mf = 0; mf < 8; mf++) {
#pragma unroll
      for (int n2 = 0; n2 < 4; n2++) {
        const int col = tn * 256 + wn + n2 * 16 + fr;
#pragma unroll
        for (int r = 0; r < 4; r++) {
          const int tt = rb0 + (mf >> 2) * 64 + (mf & 3) * 16 + r;
          float v = acc[mf][n2][r] + q.bias[col];
          if (tt >= q.t_lo && tt < q.t_hi)
            q.dst0[((size_t)bb * q.outT + (tt - q.t_lo)) * DIM + col] = v;
          else if (tt == q.t_sp)
            q.dstSp[(size_t)bb * DIM + col] = v;
        }
      }
    }
  } else {
    short* C = q.C + (ull)bz * q.sC;
#pragma unroll
    for (int mf = 0; mf < 8; mf++) {
#pragma unroll
      for (int n2 = 0; n2 < 4; n2++) {
        const int col = tn * 256 + wn + n2 * 16 + fr;
        float bn = (q.mode == 1) ? q.bias[col] : 0.0f;
#pragma unroll
        for (int r = 0; r < 4; r++) {
          const int row = tm * 256 + wm + (mf >> 2) * 64 + (mf & 3) * 16 + fq * 4 + r;
          float v = acc[mf][n2][r] + bn;
          if (q.mode == 2) v += q.bias[row];
          C[(size_t)row * q.N + col] = f2bf(v);
        }
      }
    }
  }
}

// ---------------------------------------------------------------------------
// Merged two-problem row softmax (bf16 rows, in place). Rows t < nx0 belong
// to problem 0 (SA0, Spad0, S0); the rest to problem 1. Vectorized short8.
// ---------------------------------------------------------------------------
__global__ __launch_bounds__(256)
void softmax_rows2(short* __restrict__ SA0, int Spad0, int S0, int nx0,
                   short* __restrict__ SA1, int Spad1, int S1, float scale)
{
  __shared__ float buf[SPMAX];
  __shared__ float red[8];
  int t = blockIdx.x;
  const int b = blockIdx.y;
  short* row; int Spad, S;
  if (t < nx0) { row = SA0 + ((size_t)b * Spad0 + t) * Spad0; Spad = Spad0; S = S0; }
  else { t -= nx0; row = SA1 + ((size_t)b * Spad1 + t) * Spad1; Spad = Spad1; S = S1; }
  const int tid = threadIdx.x;
  const int nv = S >> 3;

  float mx = -1e30f;
  for (int g = tid; g < nv; g += 256) {
    short8 v = ((const short8*)row)[g];
#pragma unroll
    for (int j = 0; j < 8; j++) {
      float f = bf2f(v[j]) * scale;
      buf[g * 8 + j] = f;
      mx = fmaxf(mx, f);
    }
  }
  for (int i = (nv << 3) + tid; i < S; i += 256) {
    float f = bf2f(row[i]) * scale;
    buf[i] = f;
    mx = fmaxf(mx, f);
  }
  for (int off = 32; off; off >>= 1) mx = fmaxf(mx, __shfl_down(mx, off, 64));
  if ((tid & 63) == 0) red[tid >> 6] = mx;
  __syncthreads();
  if (tid == 0) {
    float m = red[0];
    for (int w = 1; w < 4; w++) m = fmaxf(m, red[w]);
    red[0] = m;
  }
  __syncthreads();
  mx = red[0];

  float sum = 0.f;
  for (int i = tid; i < S; i += 256) {
    float e = __expf(buf[i] - mx);
    buf[i] = e;
    sum += e;
  }
  for (int off = 32; off; off >>= 1) sum += __shfl_down(sum, off, 64);
  if ((tid & 63) == 0) red[4 + (tid >> 6)] = sum;
  __syncthreads();
  if (tid == 0) red[4] = 1.0f / (red[4] + red[5] + red[6] + red[7]);
  __syncthreads();
  const float rinv = red[4];

  for (int g = tid; g < nv; g += 256) {
    short8 o;
#pragma unroll
    for (int j = 0; j < 8; j++) o[j] = f2bf(buf[g * 8 + j] * rinv);
    ((short8*)row)[g] = o;
  }
  for (int i = (nv << 3) + tid; i < S; i += 256) row[i] = f2bf(buf[i] * rinv);
  for (int i = S + tid; i < Spad; i += 256) row[i] = 0;
}

// ---------------------------------------------------------------------------
__global__ __launch_bounds__(256)
void wtrans(const float* __restrict__ W, short* __restrict__ WT)
{
  __shared__ float tile[32][33];
  const int bn = blockIdx.x * 32, bk = blockIdx.y * 32;
  const int tx = threadIdx.x & 31, ty = threadIdx.x >> 5;  // 32 x 8
#pragma unroll
  for (int j = 0; j < 4; j++)
    tile[ty + j * 8][tx] = W[(size_t)(bk + ty + j * 8) * DIM + bn + tx];
  __syncthreads();
#pragma unroll
  for (int j = 0; j < 4; j++)
    WT[(size_t)(bn + ty + j * 8) * DIM + bk + tx] = f2bf(tile[tx][ty + j * 8]);
}

// Concat bq|bk into one 2048-float bias for the fused QK projection.
__global__ __launch_bounds__(256)
void bcat(const float* __restrict__ a, const float* __restrict__ b,
          float* __restrict__ o)
{
  const int i = blockIdx.x * 256 + threadIdx.x;
  o[i] = (i < DIM) ? a[i] : b[i - DIM];
}

// ---------------------------------------------------------------------------
__global__ __launch_bounds__(256)
void assemble0(const float* __restrict__ seg0, short* __restrict__ X)
{
  const int Spad = SPMAX;
  const int b = blockIdx.y;
  const size_t lin = ((size_t)blockIdx.x * 256 + threadIdx.x) * 4;
  const int t = (int)(lin >> 10), d = (int)(lin & 1023);
  float4 v = make_float4(0.f, 0.f, 0.f, 0.f);
  if (t >= 1 && t <= SEQL)
    v = *(const float4*)(seg0 + ((size_t)b * SEQL + (t - 1)) * DIM + d);
  union { short s[4]; ull u; } o;
  o.s[0] = f2bf(v.x); o.s[1] = f2bf(v.y); o.s[2] = f2bf(v.z); o.s[3] = f2bf(v.w);
  *(ull*)(X + (size_t)b * Spad * DIM + lin) = o.u;
}

__global__ __launch_bounds__(256)
void assembleS(const float* __restrict__ seg1, const float* __restrict__ prompt,
               short* __restrict__ X)
{
  const int Spad = SPS;
  const int b = blockIdx.y;
  const size_t lin = ((size_t)blockIdx.x * 256 + threadIdx.x) * 4;
  const int t = (int)(lin >> 10), d = (int)(lin & 1023);
  float4 v = make_float4(0.f, 0.f, 0.f, 0.f);
  if (t == 0 || t == JSUM + 1)
    v = *(const float4*)(prompt + d);
  else if (t >= 1 && t <= JSUM)
    v = *(const float4*)(seg1 + ((size_t)b * SEQL + (t - 1)) * DIM + d);
  union { short s[4]; ull u; } o;
  o.s[0] = f2bf(v.x); o.s[1] = f2bf(v.y); o.s[2] = f2bf(v.z); o.s[3] = f2bf(v.w);
  *(ull*)(X + (size_t)b * Spad * DIM + lin) = o.u;
}

__global__ __launch_bounds__(256)
void assemble1(const float* __restrict__ seg0, const float* __restrict__ seg1,
               const float* __restrict__ P1, short* __restrict__ X)
{
  const int Spad = SPMAX;
  const int b = blockIdx.y;
  const size_t lin = ((size_t)blockIdx.x * 256 + threadIdx.x) * 4;
  const int t = (int)(lin >> 10), d = (int)(lin & 1023);
  float4 v = make_float4(0.f, 0.f, 0.f, 0.f);
  if (t < 32)
    v = *(const float4*)(seg0 + ((size_t)b * SEQL + (SEQL - 32 + t)) * DIM + d);
  else if (t == 32 || t == 2081)
    v = *(const float4*)(P1 + (size_t)b * DIM + d);
  else if (t >= 33 && t <= 2080)
    v = *(const float4*)(seg1 + ((size_t)b * SEQL + (t - 33)) * DIM + d);
  union { short s[4]; ull u; } o;
  o.s[0] = f2bf(v.x); o.s[1] = f2bf(v.y); o.s[2] = f2bf(v.z); o.s[3] = f2bf(v.w);
  *(ull*)(X + (size_t)b * Spad * DIM + lin) = o.u;
}

// ---------------------------------------------------------------------------
__global__ __launch_bounds__(256)
void mem_proj(const float* __restrict__ Sb, const float* __restrict__ M1,
              const float* __restrict__ Wq_mem, const float* __restrict__ bq_mem,
              const float* __restrict__ Wk_mem, const float* __restrict__ bk_mem,
              float* __restrict__ Qn, float* __restrict__ Kp)
{
  const int n = blockIdx.x * 256 + threadIdx.x;
  const int b = blockIdx.y;
  const int w = blockIdx.z;
  const float* x    = w ? M1 : Sb;
  const float* W    = w ? Wk_mem : Wq_mem;
  const float* bias = w ? bk_mem : bq_mem;
  float* o          = w ? Kp : Qn;
  const float* xr = x + (size_t)b * DIM;
  float s = bias[n];
  for (int k = 0; k < DIM; k++) s += xr[k] * W[(size_t)k * DIM + n];
  o[(size_t)b * DIM + n] = s;
}

__global__ __launch_bounds__(256)
void mem_attn(const float* __restrict__ Qn, const float* __restrict__ Kp,
              const float* __restrict__ M1, float* __restrict__ P1, float scale)
{
  __shared__ float red[256];
  __shared__ float w8[8];
  const int b = blockIdx.x, tid = threadIdx.x;
  for (int bp = 0; bp < NBATCH; bp++) {
    float p = 0.f;
    for (int k = tid; k < DIM; k += 256)
      p += Qn[(size_t)b * DIM + k] * Kp[(size_t)bp * DIM + k];
    red[tid] = p; __syncthreads();
    for (int off = 128; off; off >>= 1) {
      if (tid < off) red[tid] += red[tid + off];
      __syncthreads();
    }
    if (tid == 0) w8[bp] = red[0] * scale;
    __syncthreads();
  }
  if (tid == 0) {
    float m = w8[0];
    for (int i = 1; i < NBATCH; i++) m = fmaxf(m, w8[i]);
    float s = 0.f;
    for (int i = 0; i < NBATCH; i++) { w8[i] = __expf(w8[i] - m); s += w8[i]; }
    for (int i = 0; i < NBATCH; i++) w8[i] /= s;
  }
  __syncthreads();
  for (int d = tid; d < DIM; d += 256) {
    float a = 0.f;
    for (int bp = 0; bp < NBATCH; bp++) a += w8[bp] * M1[(size_t)bp * DIM + d];
    P1[(size_t)b * DIM + d] = a;
  }
}

// ---------------------------------------------------------------------------
extern "C" void kernel_launch(void* const* d_in, const int* in_sizes, int n_in,
                              void* d_out, int out_size, void* d_ws, size_t ws_size,
                              hipStream_t stream)
{
  const float* seg0   = (const float*)d_in[0];
  const float* seg1   = (const float*)d_in[1];
  const float* prompt = (const float*)d_in[2];
  const float* Wq_mem = (const float*)d_in[3];
  const float* bq_mem = (const float*)d_in[4];
  const float* Wk_mem = (const float*)d_in[5];
  const float* bk_mem = (const float*)d_in[6];
  const float* Wq     = (const float*)d_in[7];
  const float* bq     = (const float*)d_in[8];
  const float* Wk     = (const float*)d_in[9];
  const float* bk     = (const float*)d_in[10];
  const float* Wv     = (const float*)d_in[11];
  const float* bv     = (const float*)d_in[12];
  const float* Wo     = (const float*)d_in[13];
  const float* bo     = (const float*)d_in[14];
  float* outp = (float*)d_out;

  const size_t WSZ   = (size_t)DIM * DIM * 2;
  const size_t XSZ   = (size_t)NBATCH * SPMAX * DIM * 2;
  const size_t SASZ  = (size_t)NBATCH * SPMAX * SPMAX * 2;
  const size_t XSZS  = (size_t)NBATCH * SPS * DIM * 2;
  const size_t SASZS = (size_t)NBATCH * SPS * SPS * 2;
  const size_t VSZ   = (size_t)NBATCH * DIM * 4;

  char* p = (char*)d_ws;
  short* WqT  = (short*)p; p += WSZ;     // WqT and WkT contiguous -> fused QK
  short* WkT  = (short*)p; p += WSZ;
  short* WvT  = (short*)p; p += WSZ;
  short* WoT  = (short*)p; p += WSZ;
  short* X    = (short*)p; p += XSZ;
  short* QKb  = (short*)p; p += 2 * XSZ;   // fused Q|K, row stride 2048
  short* Vt   = (short*)p; p += XSZ;
  short* Ctx  = (short*)p; p += XSZ;
  short* SA   = (short*)p; p += SASZ;
  short* XS   = (short*)p; p += XSZS;      // phase-S buffers (coexist with ph0)
  short* QKbS = (short*)p; p += 2 * XSZS;
  short* VtS  = (short*)p; p += XSZS;
  short* CtxS = (short*)p; p += XSZS;
  short* SAS  = (short*)p; p += SASZS;
  float* M1b  = (float*)p; p += VSZ;
  float* Sb   = (float*)p; p += VSZ;
  float* Qn   = (float*)p; p += VSZ;
  float* Kp   = (float*)p; p += VSZ;
  float* P1   = (float*)p; p += VSZ;
  float* bqk  = (float*)p; p += 2 * DIM * 4;

  const float scale = 0.03125f;   // 1/sqrt(1024)
  dim3 blk(256, 1, 1);
  dim3 blkG(512, 1, 1);

  auto P = [](const short* A, ull sA, int ldA,
              const short* B, ull sB, int ldB,
              short* C, ull sC, int N, int Kd, const float* bias,
              float* dst0, int t_lo, int t_hi, int outT,
              float* dstSp, int t_sp, int Spad, int gx, int nblk,
              int mode, int swiz) {
    GemmP q{A, sA, ldA, B, sB, ldB, C, sC, N, Kd, bias,
            dst0, t_lo, t_hi, outT, dstSp, t_sp, Spad, gx, nblk, mode, swiz};
    return q;
  };

  wtrans<<<dim3(32, 32), blk, 0, stream>>>(Wq, WqT);
  wtrans<<<dim3(32, 32), blk, 0, stream>>>(Wk, WkT);
  wtrans<<<dim3(32, 32), blk, 0, stream>>>(Wv, WvT);
  wtrans<<<dim3(32, 32), blk, 0, stream>>>(Wo, WoT);
  bcat<<<dim3(8), blk, 0, stream>>>(bq, bk, bqk);

  // ---- Phase 0 (S=2050, Spad=2304) merged with Phase S (S=514, Spad=768).
  assemble0<<<dim3(SPMAX, NBATCH), blk, 0, stream>>>(seg0, X);
  assembleS<<<dim3(SPS, NBATCH), blk, 0, stream>>>(seg1, prompt, XS);

  {
    // Fused [Q|K] projection: ph0 576 blocks + phS 192.
    GemmP a = P(X, 0, DIM, WqT, 0, DIM, QKb, 0, 2048, DIM, bqk,
                nullptr, 0, 0, 0, nullptr, -1, SPMAX, NBATCH * SPMAX / 256, 576, 1, 2);
    GemmP b = P(XS, 0, DIM, WqT, 0, DIM, QKbS, 0, 2048, DIM, bqk,
                nullptr, 0, 0, 0, nullptr, -1, SPS, NBATCH * SPS / 256, 192, 1, 2);
    gemm_nt<<<dim3(768), blkG, 0, stream>>>(a, b);
  }
  {
    // Vt = NT(WvT, X) + bv[m]: 288 + 96.
    GemmP a = P(WvT, 0, DIM, X, (ull)SPMAX * DIM, DIM,
                Vt, (ull)DIM * SPMAX, SPMAX, DIM, bv,
                nullptr, 0, 0, 0, nullptr, -1, SPMAX, SPMAX / 256, 288, 2, 1);
    GemmP b = P(WvT, 0, DIM, XS, (ull)SPS * DIM, DIM,
                VtS, (ull)DIM * SPS, SPS, DIM, bv,
                nullptr, 0, 0, 0, nullptr, -1, SPS, SPS / 256, 96, 2, 1);
    gemm_nt<<<dim3(384), blkG, 0, stream>>>(a, b);
  }
  {
    // scores = Q K^T: 648 + 72.
    GemmP a = P(QKb, (ull)SPMAX * 2048, 2048, QKb + DIM, (ull)SPMAX * 2048, 2048,
                SA, (ull)SPMAX * SPMAX, SPMAX, DIM, nullptr,
                nullptr, 0, 0, 0, nullptr, -1, SPMAX, SPMAX / 256, 648, 0, 1);
    GemmP b = P(QKbS, (ull)SPS * 2048, 2048, QKbS + DIM, (ull)SPS * 2048, 2048,
                SAS, (ull)SPS * SPS, SPS, DIM, nullptr,
                nullptr, 0, 0, 0, nullptr, -1, SPS, SPS / 256, 72, 0, 1);
    gemm_nt<<<dim3(720), blkG, 0, stream>>>(a, b);
  }
  softmax_rows2<<<dim3(SPMAX + SPS, NBATCH), blk, 0, stream>>>(
      SA, SPMAX, 2050, SPMAX, SAS, SPS, 514, scale);
  {
    // ctx = attn Vt^T, K-trimmed: 288 (K=2112) + 96 (K=576).
    GemmP a = P(SA, (ull)SPMAX * SPMAX, SPMAX, Vt, (ull)DIM * SPMAX, SPMAX,
                Ctx, (ull)SPMAX * DIM, DIM, 2112, nullptr,
                nullptr, 0, 0, 0, nullptr, -1, SPMAX, DIM / 256, 288, 0, 1);
    GemmP b = P(SAS, (ull)SPS * SPS, SPS, VtS, (ull)DIM * SPS, SPS,
                CtxS, (ull)SPS * DIM, DIM, 576, nullptr,
                nullptr, 0, 0, 0, nullptr, -1, SPS, DIM / 256, 96, 0, 1);
    gemm_nt<<<dim3(384), blkG, 0, stream>>>(a, b);
  }
  {
    // H = ctx Wo^T + bo, scattered: 288 + 96.
    GemmP a = P(Ctx, 0, DIM, WoT, 0, DIM, nullptr, 0, DIM, DIM, bo,
                outp, 33, 2049, 2016, M1b, 2049, SPMAX, NBATCH * SPMAX / 256, 288, 3, 2);
    GemmP b = P(CtxS, 0, DIM, WoT, 0, DIM, nullptr, 0, DIM, DIM, bo,
                nullptr, 0, 0, 0, Sb, JSUM, SPS, NBATCH * SPS / 256, 96, 3, 2);
    gemm_nt<<<dim3(384), blkG, 0, stream>>>(a, b);
  }

  // ---- Memory attention (exact f32)
  mem_proj<<<dim3(DIM / 256, NBATCH, 2), blk, 0, stream>>>(
      Sb, M1b, Wq_mem, bq_mem, Wk_mem, bk_mem, Qn, Kp);
  mem_attn<<<dim3(NBATCH), blk, 0, stream>>>(Qn, Kp, M1b, P1, scale);

  // ---- Phase 1: backbone([seg0[-32:], P1, seg1, P1])  S=2082, Spad=2304
  assemble1<<<dim3(SPMAX, NBATCH), blk, 0, stream>>>(seg0, seg1, P1, X);
  {
    // Merged: QK-proj (576, mode1/swiz2) + Vt (288, mode2/swiz1) -> 864
    // blocks = 4 rounds vs 3+2=5 separate (both depend only on X).
    GemmP a = P(X, 0, DIM, WqT, 0, DIM, QKb, 0, 2048, DIM, bqk,
                nullptr, 0, 0, 0, nullptr, -1, SPMAX, NBATCH * SPMAX / 256, 576, 1, 2);
    GemmP b = P(WvT, 0, DIM, X, (ull)SPMAX * DIM, DIM,
                Vt, (ull)DIM * SPMAX, SPMAX, DIM, bv,
                nullptr, 0, 0, 0, nullptr, -1, SPMAX, SPMAX / 256, 288, 2, 1);
    gemm_nt<<<dim3(864), blkG, 0, stream>>>(a, b);
  }
  {
    GemmP a = P(QKb, (ull)SPMAX * 2048, 2048, QKb + DIM, (ull)SPMAX * 2048, 2048,
                SA, (ull)SPMAX * SPMAX, SPMAX, DIM, nullptr,
                nullptr, 0, 0, 0, nullptr, -1, SPMAX, SPMAX / 256, 648, 0, 1);
    gemm_nt<<<dim3(648), blkG, 0, stream>>>(a, a);
  }
  softmax_rows2<<<dim3(SPMAX, NBATCH), blk, 0, stream>>>(
      SA, SPMAX, 2082, SPMAX, SA, SPMAX, 2082, scale);
  {
    GemmP a = P(SA, (ull)SPMAX * SPMAX, SPMAX, Vt, (ull)DIM * SPMAX, SPMAX,
                Ctx, (ull)SPMAX * DIM, DIM, 2112, nullptr,
                nullptr, 0, 0, 0, nullptr, -1, SPMAX, DIM / 256, 288, 0, 1);
    gemm_nt<<<dim3(288), blkG, 0, stream>>>(a, a);
  }
  {
    GemmP a = P(Ctx, 0, DIM, WoT, 0, DIM, nullptr, 0, DIM, DIM, bo,
                outp + (size_t)NBATCH * 2016 * DIM, 33, 2081, 2048,
                nullptr, -1, SPMAX, NBATCH * SPMAX / 256, 288, 3, 2);
    gemm_nt<<<dim3(288), blkG, 0, stream>>>(a, a);
  }
}